// Round 1
// baseline (65.391 us; speedup 1.0000x reference)
//
#include <hip/hip_runtime.h>

// Problem constants (from reference): B=32, T=512, V=16, L=16, S=256, D=64, P=32
constexpr int Bc = 32;
constexpr int Tc = 512;
constexpr int Vc = 16;
constexpr int Lc = 16;
constexpr int Sc = 256;
constexpr int Dc = 64;
constexpr int Pc = 32;   // T / L

// One block per (b, v) pair. 256 threads: thread s owns shapelet s.
__global__ __launch_bounds__(256, 4) void shapelet_fused_kernel(
    const float* __restrict__ x,      // [B, T, V]
    const float* __restrict__ cand,   // [V, S, L]
    const float* __restrict__ W,      // [S, D]
    const float* __restrict__ bias,   // [D]
    float* __restrict__ out)          // [B, D, V]
{
    const int b   = blockIdx.x >> 4;   // / V
    const int v   = blockIdx.x & 15;   // % V
    const int tid = threadIdx.x;       // = shapelet index s in phase 1

    __shared__ float xs[Pc * Lc];      // 512 floats: x[b, :, v], patch-major
    __shared__ float soft[Sc];         // exp numerators
    __shared__ float rmax[4];
    __shared__ float rsum[4];
    __shared__ float pout[4][Dc];      // matmul partials

    // ---- stage x column v of batch b into LDS (xs[t] = x[b, t, v]) ----
    xs[tid]       = x[(size_t)(b * Tc + tid) * Vc + v];
    xs[tid + 256] = x[(size_t)(b * Tc + tid + 256) * Vc + v];

    // ---- candidate row s = tid into registers (coalesced float4 loads) ----
    const float4* c4 = reinterpret_cast<const float4*>(cand + ((size_t)v * Sc + tid) * Lc);
    const float4 ca = c4[0];
    const float4 cb = c4[1];
    const float4 cc = c4[2];
    const float4 cd = c4[3];

    __syncthreads();

    // ---- min over patches of squared L2 distance ----
    float dmin = 3.402823466e38f;
    #pragma unroll
    for (int p = 0; p < Pc; ++p) {
        const float4* xp = reinterpret_cast<const float4*>(xs + p * Lc);
        const float4 xa = xp[0];
        const float4 xb = xp[1];
        const float4 xc = xp[2];
        const float4 xd = xp[3];
        float t, acc;
        t = xa.x - ca.x; acc  = t * t;
        t = xa.y - ca.y; acc += t * t;
        t = xa.z - ca.z; acc += t * t;
        t = xa.w - ca.w; acc += t * t;
        t = xb.x - cb.x; acc += t * t;
        t = xb.y - cb.y; acc += t * t;
        t = xb.z - cb.z; acc += t * t;
        t = xb.w - cb.w; acc += t * t;
        t = xc.x - cc.x; acc += t * t;
        t = xc.y - cc.y; acc += t * t;
        t = xc.z - cc.z; acc += t * t;
        t = xc.w - cc.w; acc += t * t;
        t = xd.x - cd.x; acc += t * t;
        t = xd.y - cd.y; acc += t * t;
        t = xd.z - cd.z; acc += t * t;
        t = xd.w - cd.w; acc += t * t;
        dmin = fminf(dmin, acc);
    }

    const int lane = tid & 63;
    const int wid  = tid >> 6;

    // ---- block max over the 256 dist values (softmax stabilization) ----
    float m = dmin;
    #pragma unroll
    for (int off = 32; off > 0; off >>= 1)
        m = fminf(m, m) , m = fmaxf(m, __shfl_down(m, off));
    if (lane == 0) rmax[wid] = m;
    __syncthreads();
    const float blockmax = fmaxf(fmaxf(rmax[0], rmax[1]), fmaxf(rmax[2], rmax[3]));

    // ---- exp + block sum ----
    const float e = expf(dmin - blockmax);
    soft[tid] = e;                 // store numerator; normalize at the end
    float ssum = e;
    #pragma unroll
    for (int off = 32; off > 0; off >>= 1)
        ssum += __shfl_down(ssum, off);
    if (lane == 0) rsum[wid] = ssum;
    __syncthreads();

    // ---- AR head: out[b, d, v] = (sum_s soft[s] * W[s, d]) / sum + bias[d] ----
    // thread t: d = t & 63, chunk = t >> 6 handles s in [chunk*64, chunk*64+64)
    const int d     = tid & 63;
    const int chunk = tid >> 6;
    const float* Wp = W + (size_t)(chunk * 64) * Dc + d;
    const float* sp = soft + chunk * 64;
    float acc = 0.0f;
    #pragma unroll
    for (int i = 0; i < 64; ++i)
        acc += sp[i] * Wp[(size_t)i * Dc];
    pout[chunk][d] = acc;
    __syncthreads();

    if (tid < Dc) {
        const float invsum = 1.0f / (rsum[0] + rsum[1] + rsum[2] + rsum[3]);
        const float r = (pout[0][tid] + pout[1][tid] + pout[2][tid] + pout[3][tid]) * invsum
                      + bias[tid];
        out[(size_t)b * Dc * Vc + (size_t)tid * Vc + v] = r;
    }
}

extern "C" void kernel_launch(void* const* d_in, const int* in_sizes, int n_in,
                              void* d_out, int out_size, void* d_ws, size_t ws_size,
                              hipStream_t stream) {
    const float* x    = (const float*)d_in[0];   // [B, T, V]
    const float* cand = (const float*)d_in[1];   // [V, S, L]
    const float* W    = (const float*)d_in[2];   // [S, D]
    const float* bias = (const float*)d_in[3];   // [D]
    float* out = (float*)d_out;                  // [B, D, V]

    shapelet_fused_kernel<<<dim3(Bc * Vc), dim3(256), 0, stream>>>(x, cand, W, bias, out);
}

// Round 2
// 64.663 us; speedup vs baseline: 1.0112x; 1.0112x over previous
//
#include <hip/hip_runtime.h>

// Problem constants (from reference): B=32, T=512, V=16, L=16, S=256, D=64, P=32
constexpr int Bc = 32;
constexpr int Tc = 512;
constexpr int Vc = 16;
constexpr int Lc = 16;
constexpr int Sc = 256;
constexpr int Dc = 64;
constexpr int Pc = 32;   // T / L

// One block per (b, v) pair. 256 threads: thread s owns shapelet s.
// Distance via ||x||^2 - 2 x.c + ||c||^2  -> 1 FMA/element in the hot loop
// instead of sub+fma (2 ops/element).
__global__ __launch_bounds__(256, 4) void shapelet_fused_kernel(
    const float* __restrict__ x,      // [B, T, V]
    const float* __restrict__ cand,   // [V, S, L]
    const float* __restrict__ W,      // [S, D]
    const float* __restrict__ bias,   // [D]
    float* __restrict__ out)          // [B, D, V]
{
    const int b   = blockIdx.x >> 4;   // / V
    const int v   = blockIdx.x & 15;   // % V
    const int tid = threadIdx.x;       // = shapelet index s in phase 1

    __shared__ float xs[Tc];           // x[b, :, v], patch-major (contiguous t)
    __shared__ float xnorm[Pc];        // per-patch ||x_p||^2
    __shared__ float soft[Sc];         // exp numerators
    __shared__ float rmax[4];
    __shared__ float rsum[4];
    __shared__ float pout[4][Dc];      // matmul partials

    // ---- stage x column v of batch b into LDS (xs[t] = x[b, t, v]) ----
    const float xv1 = x[(size_t)(b * Tc + tid) * Vc + v];
    const float xv2 = x[(size_t)(b * Tc + tid + 256) * Vc + v];
    xs[tid]       = xv1;
    xs[tid + 256] = xv2;

    // ---- candidate row s = tid into registers (coalesced float4 loads) ----
    const float4* c4 = reinterpret_cast<const float4*>(cand + ((size_t)v * Sc + tid) * Lc);
    const float4 ca = c4[0];
    const float4 cb = c4[1];
    const float4 cc = c4[2];
    const float4 cd = c4[3];

    // ---- per-patch ||x||^2 via 16-lane shuffle reduction (no extra sync) ----
    // thread tid holds t=tid (patch tid/16) and t=tid+256 (patch tid/16 + 16)
    float sq1 = xv1 * xv1;
    float sq2 = xv2 * xv2;
    #pragma unroll
    for (int off = 1; off < 16; off <<= 1) {
        sq1 += __shfl_xor(sq1, off);
        sq2 += __shfl_xor(sq2, off);
    }
    if ((tid & 15) == 0) {
        xnorm[tid >> 4]        = sq1;
        xnorm[(tid >> 4) + 16] = sq2;
    }

    // ---- ||c||^2 once per thread ----
    float cn;
    cn  = ca.x * ca.x; cn = fmaf(ca.y, ca.y, cn); cn = fmaf(ca.z, ca.z, cn); cn = fmaf(ca.w, ca.w, cn);
    cn = fmaf(cb.x, cb.x, cn); cn = fmaf(cb.y, cb.y, cn); cn = fmaf(cb.z, cb.z, cn); cn = fmaf(cb.w, cb.w, cn);
    cn = fmaf(cc.x, cc.x, cn); cn = fmaf(cc.y, cc.y, cn); cn = fmaf(cc.z, cc.z, cn); cn = fmaf(cc.w, cc.w, cn);
    cn = fmaf(cd.x, cd.x, cn); cn = fmaf(cd.y, cd.y, cn); cn = fmaf(cd.z, cd.z, cn); cn = fmaf(cd.w, cd.w, cn);

    __syncthreads();

    // ---- min over patches: dist = ||x||^2 + ||c||^2 - 2 x.c ----
    float dmin = 3.402823466e38f;
    #pragma unroll
    for (int p = 0; p < Pc; ++p) {
        const float4* xp = reinterpret_cast<const float4*>(xs + p * Lc);
        const float4 xa = xp[0];
        const float4 xb = xp[1];
        const float4 xc = xp[2];
        const float4 xd = xp[3];
        float dot;
        dot  = xa.x * ca.x;
        dot = fmaf(xa.y, ca.y, dot); dot = fmaf(xa.z, ca.z, dot); dot = fmaf(xa.w, ca.w, dot);
        dot = fmaf(xb.x, cb.x, dot); dot = fmaf(xb.y, cb.y, dot); dot = fmaf(xb.z, cb.z, dot); dot = fmaf(xb.w, cb.w, dot);
        dot = fmaf(xc.x, cc.x, dot); dot = fmaf(xc.y, cc.y, dot); dot = fmaf(xc.z, cc.z, dot); dot = fmaf(xc.w, cc.w, dot);
        dot = fmaf(xd.x, cd.x, dot); dot = fmaf(xd.y, cd.y, dot); dot = fmaf(xd.z, cd.z, dot); dot = fmaf(xd.w, cd.w, dot);
        const float dist = fmaf(-2.0f, dot, xnorm[p] + cn);
        dmin = fminf(dmin, dist);
    }

    const int lane = tid & 63;
    const int wid  = tid >> 6;

    // ---- block max over the 256 dist values (softmax stabilization) ----
    float m = dmin;
    #pragma unroll
    for (int off = 32; off > 0; off >>= 1)
        m = fmaxf(m, __shfl_down(m, off));
    if (lane == 0) rmax[wid] = m;
    __syncthreads();
    const float blockmax = fmaxf(fmaxf(rmax[0], rmax[1]), fmaxf(rmax[2], rmax[3]));

    // ---- exp + block sum ----
    const float e = expf(dmin - blockmax);
    soft[tid] = e;                 // store numerator; normalize at the end
    float ssum = e;
    #pragma unroll
    for (int off = 32; off > 0; off >>= 1)
        ssum += __shfl_down(ssum, off);
    if (lane == 0) rsum[wid] = ssum;
    __syncthreads();

    // ---- AR head: out[b, d, v] = (sum_s soft[s] * W[s, d]) / sum + bias[d] ----
    // thread t: d = t & 63, chunk = t >> 6 handles s in [chunk*64, chunk*64+64)
    const int d     = tid & 63;
    const int chunk = tid >> 6;
    const float* Wp = W + (size_t)(chunk * 64) * Dc + d;
    const float* sp = soft + chunk * 64;
    float acc = 0.0f;
    #pragma unroll
    for (int i = 0; i < 64; ++i)
        acc = fmaf(sp[i], Wp[(size_t)i * Dc], acc);
    pout[chunk][d] = acc;
    __syncthreads();

    if (tid < Dc) {
        const float invsum = 1.0f / (rsum[0] + rsum[1] + rsum[2] + rsum[3]);
        const float r = (pout[0][tid] + pout[1][tid] + pout[2][tid] + pout[3][tid]) * invsum
                      + bias[tid];
        out[(size_t)b * Dc * Vc + (size_t)tid * Vc + v] = r;
    }
}

extern "C" void kernel_launch(void* const* d_in, const int* in_sizes, int n_in,
                              void* d_out, int out_size, void* d_ws, size_t ws_size,
                              hipStream_t stream) {
    const float* x    = (const float*)d_in[0];   // [B, T, V]
    const float* cand = (const float*)d_in[1];   // [V, S, L]
    const float* W    = (const float*)d_in[2];   // [S, D]
    const float* bias = (const float*)d_in[3];   // [D]
    float* out = (float*)d_out;                  // [B, D, V]

    shapelet_fused_kernel<<<dim3(Bc * Vc), dim3(256), 0, stream>>>(x, cand, W, bias, out);
}